// Round 11
// baseline (284.158 us; speedup 1.0000x reference)
//
#include <hip/hip_runtime.h>
#include <hip/hip_bf16.h>
#include <math.h>
#include <stdint.h>

#define BATCH   4
#define SEQ     2048
#define DMODEL  512
#define NHEADS  8
#define HDIM    64
#define QKV_N   (3*DMODEL)   // 1536

typedef short bf8  __attribute__((ext_vector_type(8)));   // 8 bf16 (4 VGPRs)
typedef float f32x4 __attribute__((ext_vector_type(4)));  // 4 fp32 acc

#define MFMA16(a,b,c) __builtin_amdgcn_mfma_f32_16x16x32_bf16((a),(b),(c),0,0,0)

// Q pre-scale: 1/sqrt(64) * log2(e)  (so attention uses exp2f -> bare v_exp_f32)
#define QSCALE 0.18033688011112042f

__device__ inline unsigned short f2bf(float f){      // RNE fp32->bf16
  unsigned int u = __float_as_uint(f);
  u += 0x7FFFu + ((u >> 16) & 1u);
  return (unsigned short)(u >> 16);
}

__device__ inline unsigned int pack_bf2(float a, float b){  // v_cvt_pk_bf16_f32
  __hip_bfloat162 h = __float22bfloat162_rn(make_float2(a, b));
  return *reinterpret_cast<unsigned int*>(&h);
}

// global -> LDS direct DMA, 16 B per lane. LDS dest = wave-uniform base +
// lane*16 (so the LDS tile must be unpadded, in lane order).
__device__ __forceinline__ void gload_lds16(const unsigned short* g,
                                            unsigned short* l){
  __builtin_amdgcn_global_load_lds(
      (const __attribute__((address_space(1))) unsigned int*)g,
      (__attribute__((address_space(3))) unsigned int*)l,
      16, 0, 0);
}

// ---------------------------------------------------------------------------
// Fused prepass: cast x -> bf16 (blocks 0..2047), transpose+cast W_qkv
// (blocks 2048..2239), transpose+cast W_out (blocks 2240..2303).
// ---------------------------------------------------------------------------
__global__ __launch_bounds__(256) void prep(
    const float* __restrict__ x, const float* __restrict__ Wqkv,
    const float* __restrict__ Wout, unsigned short* __restrict__ Xh,
    unsigned short* __restrict__ WqkvT, unsigned short* __restrict__ WoutT)
{
  __shared__ unsigned short Ts[64][72];
  const int t = threadIdx.x;
  const int bx = blockIdx.x;
  if (bx < 2048) {
    const int i = bx*256 + t;
    const float4 a = reinterpret_cast<const float4*>(x)[2*i];
    const float4 b = reinterpret_cast<const float4*>(x)[2*i+1];
    uint4 o; unsigned short* us = reinterpret_cast<unsigned short*>(&o);
    us[0]=f2bf(a.x); us[1]=f2bf(a.y); us[2]=f2bf(a.z); us[3]=f2bf(a.w);
    us[4]=f2bf(b.x); us[5]=f2bf(b.y); us[6]=f2bf(b.z); us[7]=f2bf(b.w);
    reinterpret_cast<uint4*>(Xh)[i] = o;
    return;
  }
  const float* in; unsigned short* out; int R, C, gx, gy;
  if (bx < 2048 + 192) {
    const int bid = bx - 2048;
    gx = bid % 24; gy = bid / 24; in = Wqkv; out = WqkvT; R = DMODEL; C = QKV_N;
  } else {
    const int bid = bx - 2240;
    gx = bid % 8;  gy = bid / 8;  in = Wout; out = WoutT; R = DMODEL; C = DMODEL;
  }
  const int r0 = gy<<6, c0 = gx<<6;
  const int rr = t>>2, cs = (t&3)<<4;
#pragma unroll
  for (int p=0;p<4;++p){
    float4 v = *reinterpret_cast<const float4*>(in + (size_t)(r0+rr)*C + c0 + cs + p*4);
    Ts[rr][cs+p*4+0]=f2bf(v.x); Ts[rr][cs+p*4+1]=f2bf(v.y);
    Ts[rr][cs+p*4+2]=f2bf(v.z); Ts[rr][cs+p*4+3]=f2bf(v.w);
  }
  __syncthreads();
  const int cc = t>>2, rs = (t&3)<<4;
#pragma unroll
  for (int p=0;p<4;++p){
    ushort4 o;
    o.x = Ts[rs+p*4+0][cc]; o.y = Ts[rs+p*4+1][cc];
    o.z = Ts[rs+p*4+2][cc]; o.w = Ts[rs+p*4+3][cc];
    *reinterpret_cast<ushort4*>(out + (size_t)(c0+cc)*R + r0 + rs + p*4) = o;
  }
}

// ---------------------------------------------------------------------------
// MFMA GEMM A (m97 structure): QKV = Xh @ WqkvT^T -> natural [8192][1536].
// Q-part columns (c%192 < 64) pre-scaled by QSCALE (1/8 * log2 e).
// ---------------------------------------------------------------------------
__global__ __launch_bounds__(256) void gemm_qkv_mfma(
    const unsigned short* __restrict__ A, const unsigned short* __restrict__ Bt,
    unsigned short* __restrict__ QKV)
{
  __shared__ unsigned short As[128][64];
  __shared__ unsigned short Bs[128][64];
  const int t = threadIdx.x;
  const int w = t>>6, lane = t&63, quad = lane>>4, l15 = lane&15;
  const int wr = (w>>1)<<6, wc = (w&1)<<6;
  const int m0 = blockIdx.y<<7, n0 = blockIdx.x<<7;
  const int row = t>>3, seg = t&7;
  const unsigned short* Agp = A  + (size_t)(m0+row)*DMODEL + seg*8;
  const unsigned short* Bgp = Bt + (size_t)(n0+row)*DMODEL + seg*8;
  f32x4 acc[4][4];
#pragma unroll
  for (int i=0;i<4;++i)
#pragma unroll
    for (int j=0;j<4;++j) acc[i][j] = (f32x4){0.f,0.f,0.f,0.f};

  for (int k0=0;k0<DMODEL;k0+=64){
    __syncthreads();
#pragma unroll
    for (int p=0;p<4;++p){
      gload_lds16(Agp + (size_t)p*32*DMODEL + k0, &As[(w<<3)+(p<<5)][0]);
      gload_lds16(Bgp + (size_t)p*32*DMODEL + k0, &Bs[(w<<3)+(p<<5)][0]);
    }
    __syncthreads();
#pragma unroll
    for (int ks=0;ks<2;++ks){
      bf8 af[4], bfr[4];
#pragma unroll
      for (int mi=0;mi<4;++mi)
        af[mi]  = *reinterpret_cast<const bf8*>(&As[wr+mi*16+l15][ks*32+quad*8]);
#pragma unroll
      for (int nj=0;nj<4;++nj)
        bfr[nj] = *reinterpret_cast<const bf8*>(&Bs[wc+(l15<<2)+nj][ks*32+quad*8]);
#pragma unroll
      for (int mi=0;mi<4;++mi)
#pragma unroll
        for (int nj=0;nj<4;++nj) acc[mi][nj] = MFMA16(af[mi], bfr[nj], acc[mi][nj]);
    }
  }
  const int cbase = n0 + wc + (l15<<2);
  bool isq[4];
#pragma unroll
  for (int nj=0;nj<4;++nj) isq[nj] = ((cbase+nj) % 192) < 64;
#pragma unroll
  for (int mi=0;mi<4;++mi)
#pragma unroll
    for (int i=0;i<4;++i){
      const int m = m0 + wr + mi*16 + quad*4 + i;
      unsigned long long pk = 0;
#pragma unroll
      for (int nj=0;nj<4;++nj){
        float v = acc[mi][nj][i];
        if (isq[nj]) v *= QSCALE;
        pk |= (unsigned long long)f2bf(v) << (16*nj);
      }
      *reinterpret_cast<unsigned long long*>(QKV + (size_t)m*QKV_N + cbase) = pk;
    }
}

// ---------------------------------------------------------------------------
// V^T builder: VT[bh][d][s] from natural qkv.
// ---------------------------------------------------------------------------
__global__ __launch_bounds__(256) void v_transpose(
    const unsigned short* __restrict__ QKV, unsigned short* __restrict__ VT)
{
  __shared__ unsigned short Td[64][76];
  const int t = threadIdx.x;
  const int bh = blockIdx.y, b = bh>>3, hp = bh&7;
  const int s0 = blockIdx.x<<6;
  const size_t rbase = (size_t)(b*SEQ + hp*256);
  const int sr = t>>2, db = (t&3)<<4;
  const int kk = s0 + sr;
  const unsigned short* vp =
      QKV + (rbase + (kk>>3))*QKV_N + (kk&7)*192 + 128 + db;
  uint4 a = *reinterpret_cast<const uint4*>(vp);
  uint4 c = *reinterpret_cast<const uint4*>(vp + 8);
  const unsigned short* ua = reinterpret_cast<const unsigned short*>(&a);
  const unsigned short* uc = reinterpret_cast<const unsigned short*>(&c);
#pragma unroll
  for (int j=0;j<8;++j) Td[db+j][sr]   = ua[j];
#pragma unroll
  for (int j=0;j<8;++j) Td[db+8+j][sr] = uc[j];
  __syncthreads();
  const int L = t&15, d0 = t>>4;
  unsigned short* Op = VT + (size_t)bh*HDIM*SEQ + s0 + (L<<2);
#pragma unroll
  for (int cc=0;cc<4;++cc){
    const int d = d0 + (cc<<4);
    *reinterpret_cast<unsigned long long*>(Op + (size_t)d*SEQ) =
        *reinterpret_cast<const unsigned long long*>(&Td[d][L<<2]);
  }
}

// ---------------------------------------------------------------------------
// MFMA flash attention v7: 128-q blocks of TWO waves, 64 q/wave (4 strips).
// K/V frag reads + staging amortized over 2x queries per wave vs r8.
// r8 semantics: cndmask masking, per-lane lsum, final shuffles. exp2f only.
// rho-permuted K staging (B-frag row nf*16+l15 = key 4*l15+nf).
// ---------------------------------------------------------------------------
__global__ __launch_bounds__(128, 2) void attn_mfma(
    const unsigned short* __restrict__ QKV, const unsigned short* __restrict__ VT,
    const int* __restrict__ mask, unsigned short* __restrict__ O)
{
  __shared__ unsigned long long mbits[32];   // 2048-bit validity
  __shared__ unsigned short Ks[64][72];      // rho-permuted K tile [row][d]
  __shared__ unsigned short Vs[64][72];      // V^T tile [d][key]
  __shared__ unsigned short Pl[2][64][72];   // wave-private P [q][key]
  const int t = threadIdx.x;                 // 0..127
  const int w = t>>6, lane = t&63, quad = lane>>4, l15 = lane&15;
  const int bh = blockIdx.y, b = bh>>3, hp = bh&7;
  const int q0 = blockIdx.x<<7;              // 128 queries per block
  const int qs = q0 + (w<<6);                // 64 per wave
  const int* mb = mask + b*SEQ;
  const f32x4 Z4 = {0.f,0.f,0.f,0.f};
#pragma unroll
  for (int i=0;i<16;++i){
    const unsigned long long bal = __ballot(mb[i*128 + t] != 0);
    if (lane == 0) mbits[2*i + w] = bal;
  }

  const size_t rbase = (size_t)(b*SEQ + hp*256);   // qkv row base for this bh
  bf8 qf[4][2];
#pragma unroll
  for (int a=0;a<4;++a){
    const int q = qs + a*16 + l15;
    const unsigned short* qp =
        QKV + (rbase + (q>>3))*QKV_N + (q&7)*192 + (quad<<3);
    qf[a][0] = *reinterpret_cast<const bf8*>(qp);
    qf[a][1] = *reinterpret_cast<const bf8*>(qp + 32);
  }
  const unsigned short* Vg = VT + (size_t)bh*HDIM*SEQ;

  // staging: 128 threads, each stages 64 B of K row srow and 64 B of V row
  const int srow = t>>1, shalf = (t&1)<<5;          // key/d row, 32-short col
  const int krow = ((srow&3)<<4) + (srow>>2);       // rho(srow)

  f32x4 of[4][4]; float lsum[4][4];
#pragma unroll
  for (int a=0;a<4;++a)
#pragma unroll
    for (int i=0;i<4;++i){ of[a][i]=Z4; lsum[a][i]=0.f; }

  // prefetch tile 0 into registers (4 uint4 K + 4 uint4 V per thread)
  uint4 gk[4], gv[4];
  {
    const unsigned short* kp =
        QKV + (rbase + (srow>>3))*QKV_N + (srow&7)*192 + 64 + shalf;
    const unsigned short* vp = Vg + (size_t)srow*SEQ + shalf;
#pragma unroll
    for (int j=0;j<4;++j){
      gk[j] = *reinterpret_cast<const uint4*>(kp + 8*j);
      gv[j] = *reinterpret_cast<const uint4*>(vp + 8*j);
    }
  }
  __syncthreads();                                   // mbits visible

  for (int kt=0; kt<SEQ; kt+=64){
#pragma unroll
    for (int j=0;j<4;++j){
      *reinterpret_cast<uint4*>(&Ks[krow][shalf + 8*j]) = gk[j];
      *reinterpret_cast<uint4*>(&Vs[srow][shalf + 8*j]) = gv[j];
    }
    __syncthreads();                                 // tiles visible

    if (kt + 64 < SEQ){                              // prefetch tile t+1
      const int kk = kt + 64 + srow;
      const unsigned short* kp =
          QKV + (rbase + (kk>>3))*QKV_N + (kk&7)*192 + 64 + shalf;
      const unsigned short* vp = Vg + (size_t)srow*SEQ + kt + 64 + shalf;
#pragma unroll
      for (int j=0;j<4;++j){
        gk[j] = *reinterpret_cast<const uint4*>(kp + 8*j);
        gv[j] = *reinterpret_cast<const uint4*>(vp + 8*j);
      }
    }

    const unsigned int msel =
        (unsigned int)(mbits[kt>>6] >> (l15<<2)) & 0xFu;

    {
      bf8 kf0[4], kf1[4];
#pragma unroll
      for (int nf=0;nf<4;++nf){
        kf0[nf] = *reinterpret_cast<const bf8*>(&Ks[nf*16+l15][quad<<3]);
        kf1[nf] = *reinterpret_cast<const bf8*>(&Ks[nf*16+l15][32+(quad<<3)]);
      }
#pragma unroll
      for (int a=0;a<4;++a){
        f32x4 sc[4];
#pragma unroll
        for (int nf=0;nf<4;++nf){
          f32x4 s = MFMA16(qf[a][0], kf0[nf], Z4);
          sc[nf] = MFMA16(qf[a][1], kf1[nf], s);
        }
        float pv[4][4];
#pragma unroll
        for (int nf=0;nf<4;++nf){
          const bool on = (msel >> nf) & 1u;
#pragma unroll
          for (int i=0;i<4;++i)
            pv[nf][i] = on ? exp2f(sc[nf][i]) : 0.f;  // Q pre-scaled log2e/8
        }
#pragma unroll
        for (int i=0;i<4;++i)
          lsum[a][i] += (pv[0][i]+pv[1][i]) + (pv[2][i]+pv[3][i]);
#pragma unroll
        for (int i=0;i<4;++i){
          const unsigned int lo = pack_bf2(pv[0][i], pv[1][i]);
          const unsigned int hi = pack_bf2(pv[2][i], pv[3][i]);
          *reinterpret_cast<unsigned long long*>(&Pl[w][a*16+(quad<<2)+i][l15<<2]) =
              ((unsigned long long)hi<<32) | lo;
        }
      }
    }

    bf8 pa[4][2];
#pragma unroll
    for (int a=0;a<4;++a){
      pa[a][0] = *reinterpret_cast<const bf8*>(&Pl[w][a*16+l15][quad<<3]);
      pa[a][1] = *reinterpret_cast<const bf8*>(&Pl[w][a*16+l15][32+(quad<<3)]);
    }
#pragma unroll
    for (int nf=0;nf<4;++nf){
      const bf8 v0 = *reinterpret_cast<const bf8*>(&Vs[nf*16+l15][quad<<3]);
      const bf8 v1 = *reinterpret_cast<const bf8*>(&Vs[nf*16+l15][32+(quad<<3)]);
#pragma unroll
      for (int a=0;a<4;++a){
        f32x4 o = MFMA16(pa[a][0], v0, of[a][nf]);
        of[a][nf] = MFMA16(pa[a][1], v1, o);
      }
    }
    __syncthreads();                                 // readers done, bufs free
  }

#pragma unroll
  for (int a=0;a<4;++a)
#pragma unroll
    for (int i=0;i<4;++i){
      float s = lsum[a][i];
      s += __shfl_xor(s,1); s += __shfl_xor(s,2);
      s += __shfl_xor(s,4); s += __shfl_xor(s,8);
      lsum[a][i] = s;
    }
  unsigned short* Op = O + (size_t)bh*SEQ*HDIM;
#pragma unroll
  for (int a=0;a<4;++a){
    const unsigned long long qw = mbits[(qs + a*16) >> 6];
#pragma unroll
    for (int i=0;i<4;++i){
      const int q = qs + a*16 + (quad<<2) + i;
      const bool qv = (qw >> (q & 63)) & 1ull;
      const float inv = (qv && lsum[a][i] > 0.f) ? 1.f/lsum[a][i] : 0.f;
#pragma unroll
      for (int nf=0;nf<4;++nf)
        Op[(size_t)q*HDIM + (nf<<4) + l15] = f2bf(of[a][nf][i]*inv);
    }
  }
}

// ---------------------------------------------------------------------------
// MFMA GEMM C (m97 structure): out = Ob @ WoutT^T, fp32 float4 stores.
// ---------------------------------------------------------------------------
__global__ __launch_bounds__(256) void gemm_out_mfma(
    const unsigned short* __restrict__ A, const unsigned short* __restrict__ Bt,
    float* __restrict__ Out)
{
  __shared__ unsigned short As[128][64];
  __shared__ unsigned short Bs[128][64];
  const int t = threadIdx.x;
  const int w = t>>6, lane = t&63, quad = lane>>4, l15 = lane&15;
  const int wr = (w>>1)<<6, wc = (w&1)<<6;
  const int m0 = blockIdx.y<<7, n0 = blockIdx.x<<7;
  const int row = t>>3, seg = t&7;
  const unsigned short* Agp = A  + (size_t)(m0+row)*DMODEL + seg*8;
  const unsigned short* Bgp = Bt + (size_t)(n0+row)*DMODEL + seg*8;
  f32x4 acc[4][4];
#pragma unroll
  for (int i=0;i<4;++i)
#pragma unroll
    for (int j=0;j<4;++j) acc[i][j] = (f32x4){0.f,0.f,0.f,0.f};

  for (int k0=0;k0<DMODEL;k0+=64){
    __syncthreads();
#pragma unroll
    for (int p=0;p<4;++p){
      gload_lds16(Agp + (size_t)p*32*DMODEL + k0, &As[(w<<3)+(p<<5)][0]);
      gload_lds16(Bgp + (size_t)p*32*DMODEL + k0, &Bs[(w<<3)+(p<<5)][0]);
    }
    __syncthreads();
#pragma unroll
    for (int ks=0;ks<2;++ks){
      bf8 af[4], bfr[4];
#pragma unroll
      for (int mi=0;mi<4;++mi)
        af[mi]  = *reinterpret_cast<const bf8*>(&As[wr+mi*16+l15][ks*32+quad*8]);
#pragma unroll
      for (int nj=0;nj<4;++nj)
        bfr[nj] = *reinterpret_cast<const bf8*>(&Bs[wc+(l15<<2)+nj][ks*32+quad*8]);
#pragma unroll
      for (int mi=0;mi<4;++mi)
#pragma unroll
        for (int nj=0;nj<4;++nj) acc[mi][nj] = MFMA16(af[mi], bfr[nj], acc[mi][nj]);
    }
  }
  const int cbase = n0 + wc + (l15<<2);
#pragma unroll
  for (int mi=0;mi<4;++mi)
#pragma unroll
    for (int i=0;i<4;++i){
      const int m = m0 + wr + mi*16 + quad*4 + i;
      const float4 o = make_float4(acc[mi][0][i], acc[mi][1][i],
                                   acc[mi][2][i], acc[mi][3][i]);
      *reinterpret_cast<float4*>(Out + (size_t)m*DMODEL + cbase) = o;
    }
}

// ---------------------------------------------------------------------------
extern "C" void kernel_launch(void* const* d_in, const int* in_sizes, int n_in,
                              void* d_out, int out_size, void* d_ws, size_t ws_size,
                              hipStream_t stream) {
  (void)in_sizes; (void)n_in; (void)out_size; (void)ws_size;
  const float* x     = (const float*)d_in[0];
  const int*   pmask = (const int*)d_in[2];
  const float* Wqkv  = (const float*)d_in[3];
  const float* Wout  = (const float*)d_in[4];
  float* out = (float*)d_out;

  const size_t per = (size_t)BATCH*NHEADS*SEQ*HDIM;     // 4,194,304
  unsigned short* Xh    = (unsigned short*)d_ws;
  unsigned short* WqkvT = Xh    + (size_t)8192*512;
  unsigned short* WoutT = WqkvT + (size_t)1536*512;
  unsigned short* QKVb  = WoutT + (size_t)512*512;
  unsigned short* VbT   = QKVb  + (size_t)8192*QKV_N;
  unsigned short* Ob    = VbT + per;                    // ~52 MB total

  prep<<<2304, 256, 0, stream>>>(x, Wqkv, Wout, Xh, WqkvT, WoutT);
  gemm_qkv_mfma<<<dim3(QKV_N/128, 8192/128), 256, 0, stream>>>(Xh, WqkvT, QKVb);
  v_transpose<<<dim3(SEQ/64, BATCH*NHEADS), 256, 0, stream>>>(QKVb, VbT);
  attn_mfma<<<dim3(SEQ/128, BATCH*NHEADS), 128, 0, stream>>>(QKVb, VbT, pmask, Ob);
  gemm_out_mfma<<<dim3(DMODEL/128, 8192/128), 256, 0, stream>>>(Ob, WoutT, out);
}

// Round 12
// 209.837 us; speedup vs baseline: 1.3542x; 1.3542x over previous
//
#include <hip/hip_runtime.h>
#include <hip/hip_bf16.h>
#include <math.h>
#include <stdint.h>

#define BATCH   4
#define SEQ     2048
#define DMODEL  512
#define NHEADS  8
#define HDIM    64
#define QKV_N   (3*DMODEL)   // 1536

typedef short bf8  __attribute__((ext_vector_type(8)));   // 8 bf16 (4 VGPRs)
typedef float f32x4 __attribute__((ext_vector_type(4)));  // 4 fp32 acc

#define MFMA16(a,b,c) __builtin_amdgcn_mfma_f32_16x16x32_bf16((a),(b),(c),0,0,0)

// Q pre-scale: 1/sqrt(64) * log2(e)  (so attention uses exp2f -> bare v_exp_f32)
#define QSCALE 0.18033688011112042f

__device__ inline unsigned short f2bf(float f){      // RNE fp32->bf16
  unsigned int u = __float_as_uint(f);
  u += 0x7FFFu + ((u >> 16) & 1u);
  return (unsigned short)(u >> 16);
}

__device__ inline unsigned int pack_bf2(float a, float b){  // v_cvt_pk_bf16_f32
  __hip_bfloat162 h = __float22bfloat162_rn(make_float2(a, b));
  return *reinterpret_cast<unsigned int*>(&h);
}

// global -> LDS direct DMA, 16 B per lane. LDS dest = wave-uniform base +
// lane*16 (so the LDS tile must be unpadded, in lane order).
__device__ __forceinline__ void gload_lds16(const unsigned short* g,
                                            unsigned short* l){
  __builtin_amdgcn_global_load_lds(
      (const __attribute__((address_space(1))) unsigned int*)g,
      (__attribute__((address_space(3))) unsigned int*)l,
      16, 0, 0);
}

// ---------------------------------------------------------------------------
// Fused prepass: cast x -> bf16 (blocks 0..2047), transpose+cast W_qkv
// (blocks 2048..2239), transpose+cast W_out (blocks 2240..2303).
// ---------------------------------------------------------------------------
__global__ __launch_bounds__(256) void prep(
    const float* __restrict__ x, const float* __restrict__ Wqkv,
    const float* __restrict__ Wout, unsigned short* __restrict__ Xh,
    unsigned short* __restrict__ WqkvT, unsigned short* __restrict__ WoutT)
{
  __shared__ unsigned short Ts[64][72];
  const int t = threadIdx.x;
  const int bx = blockIdx.x;
  if (bx < 2048) {
    const int i = bx*256 + t;
    const float4 a = reinterpret_cast<const float4*>(x)[2*i];
    const float4 b = reinterpret_cast<const float4*>(x)[2*i+1];
    uint4 o; unsigned short* us = reinterpret_cast<unsigned short*>(&o);
    us[0]=f2bf(a.x); us[1]=f2bf(a.y); us[2]=f2bf(a.z); us[3]=f2bf(a.w);
    us[4]=f2bf(b.x); us[5]=f2bf(b.y); us[6]=f2bf(b.z); us[7]=f2bf(b.w);
    reinterpret_cast<uint4*>(Xh)[i] = o;
    return;
  }
  const float* in; unsigned short* out; int R, C, gx, gy;
  if (bx < 2048 + 192) {
    const int bid = bx - 2048;
    gx = bid % 24; gy = bid / 24; in = Wqkv; out = WqkvT; R = DMODEL; C = QKV_N;
  } else {
    const int bid = bx - 2240;
    gx = bid % 8;  gy = bid / 8;  in = Wout; out = WoutT; R = DMODEL; C = DMODEL;
  }
  const int r0 = gy<<6, c0 = gx<<6;
  const int rr = t>>2, cs = (t&3)<<4;
#pragma unroll
  for (int p=0;p<4;++p){
    float4 v = *reinterpret_cast<const float4*>(in + (size_t)(r0+rr)*C + c0 + cs + p*4);
    Ts[rr][cs+p*4+0]=f2bf(v.x); Ts[rr][cs+p*4+1]=f2bf(v.y);
    Ts[rr][cs+p*4+2]=f2bf(v.z); Ts[rr][cs+p*4+3]=f2bf(v.w);
  }
  __syncthreads();
  const int cc = t>>2, rs = (t&3)<<4;
#pragma unroll
  for (int p=0;p<4;++p){
    ushort4 o;
    o.x = Ts[rs+p*4+0][cc]; o.y = Ts[rs+p*4+1][cc];
    o.z = Ts[rs+p*4+2][cc]; o.w = Ts[rs+p*4+3][cc];
    *reinterpret_cast<ushort4*>(out + (size_t)(c0+cc)*R + r0 + rs + p*4) = o;
  }
}

// ---------------------------------------------------------------------------
// MFMA GEMM A (m97 structure): QKV = Xh @ WqkvT^T -> natural [8192][1536].
// Q-part columns (c%192 < 64) pre-scaled by QSCALE (1/8 * log2 e).
// ---------------------------------------------------------------------------
__global__ __launch_bounds__(256) void gemm_qkv_mfma(
    const unsigned short* __restrict__ A, const unsigned short* __restrict__ Bt,
    unsigned short* __restrict__ QKV)
{
  __shared__ unsigned short As[128][64];
  __shared__ unsigned short Bs[128][64];
  const int t = threadIdx.x;
  const int w = t>>6, lane = t&63, quad = lane>>4, l15 = lane&15;
  const int wr = (w>>1)<<6, wc = (w&1)<<6;
  const int m0 = blockIdx.y<<7, n0 = blockIdx.x<<7;
  const int row = t>>3, seg = t&7;
  const unsigned short* Agp = A  + (size_t)(m0+row)*DMODEL + seg*8;
  const unsigned short* Bgp = Bt + (size_t)(n0+row)*DMODEL + seg*8;
  f32x4 acc[4][4];
#pragma unroll
  for (int i=0;i<4;++i)
#pragma unroll
    for (int j=0;j<4;++j) acc[i][j] = (f32x4){0.f,0.f,0.f,0.f};

  for (int k0=0;k0<DMODEL;k0+=64){
    __syncthreads();
#pragma unroll
    for (int p=0;p<4;++p){
      gload_lds16(Agp + (size_t)p*32*DMODEL + k0, &As[(w<<3)+(p<<5)][0]);
      gload_lds16(Bgp + (size_t)p*32*DMODEL + k0, &Bs[(w<<3)+(p<<5)][0]);
    }
    __syncthreads();
#pragma unroll
    for (int ks=0;ks<2;++ks){
      bf8 af[4], bfr[4];
#pragma unroll
      for (int mi=0;mi<4;++mi)
        af[mi]  = *reinterpret_cast<const bf8*>(&As[wr+mi*16+l15][ks*32+quad*8]);
#pragma unroll
      for (int nj=0;nj<4;++nj)
        bfr[nj] = *reinterpret_cast<const bf8*>(&Bs[wc+(l15<<2)+nj][ks*32+quad*8]);
#pragma unroll
      for (int mi=0;mi<4;++mi)
#pragma unroll
        for (int nj=0;nj<4;++nj) acc[mi][nj] = MFMA16(af[mi], bfr[nj], acc[mi][nj]);
    }
  }
  const int cbase = n0 + wc + (l15<<2);
  bool isq[4];
#pragma unroll
  for (int nj=0;nj<4;++nj) isq[nj] = ((cbase+nj) % 192) < 64;
#pragma unroll
  for (int mi=0;mi<4;++mi)
#pragma unroll
    for (int i=0;i<4;++i){
      const int m = m0 + wr + mi*16 + quad*4 + i;
      unsigned long long pk = 0;
#pragma unroll
      for (int nj=0;nj<4;++nj){
        float v = acc[mi][nj][i];
        if (isq[nj]) v *= QSCALE;
        pk |= (unsigned long long)f2bf(v) << (16*nj);
      }
      *reinterpret_cast<unsigned long long*>(QKV + (size_t)m*QKV_N + cbase) = pk;
    }
}

// ---------------------------------------------------------------------------
// V^T builder: VT[bh][d][s] from natural qkv.
// ---------------------------------------------------------------------------
__global__ __launch_bounds__(256) void v_transpose(
    const unsigned short* __restrict__ QKV, unsigned short* __restrict__ VT)
{
  __shared__ unsigned short Td[64][76];
  const int t = threadIdx.x;
  const int bh = blockIdx.y, b = bh>>3, hp = bh&7;
  const int s0 = blockIdx.x<<6;
  const size_t rbase = (size_t)(b*SEQ + hp*256);
  const int sr = t>>2, db = (t&3)<<4;
  const int kk = s0 + sr;
  const unsigned short* vp =
      QKV + (rbase + (kk>>3))*QKV_N + (kk&7)*192 + 128 + db;
  uint4 a = *reinterpret_cast<const uint4*>(vp);
  uint4 c = *reinterpret_cast<const uint4*>(vp + 8);
  const unsigned short* ua = reinterpret_cast<const unsigned short*>(&a);
  const unsigned short* uc = reinterpret_cast<const unsigned short*>(&c);
#pragma unroll
  for (int j=0;j<8;++j) Td[db+j][sr]   = ua[j];
#pragma unroll
  for (int j=0;j<8;++j) Td[db+8+j][sr] = uc[j];
  __syncthreads();
  const int L = t&15, d0 = t>>4;
  unsigned short* Op = VT + (size_t)bh*HDIM*SEQ + s0 + (L<<2);
#pragma unroll
  for (int cc=0;cc<4;++cc){
    const int d = d0 + (cc<<4);
    *reinterpret_cast<unsigned long long*>(Op + (size_t)d*SEQ) =
        *reinterpret_cast<const unsigned long long*>(&Td[d][L<<2]);
  }
}

// ---------------------------------------------------------------------------
// MFMA flash attention (r8 config, exp2f): 128-q tile, 4 waves, 32 q/wave.
// LDS-staged K & V^T tiles, register prefetch, no-max softmax, rho-permuted
// K staging (B-frag row nf*16+l15 = key 4*l15+nf), cndmask masking,
// per-lane lsum + final shuffles.
// ---------------------------------------------------------------------------
__global__ __launch_bounds__(256, 2) void attn_mfma(
    const unsigned short* __restrict__ QKV, const unsigned short* __restrict__ VT,
    const int* __restrict__ mask, unsigned short* __restrict__ O)
{
  __shared__ unsigned long long mbits[32];   // 2048-bit validity
  __shared__ unsigned short Ks[64][72];      // rho-permuted K tile [row][d]
  __shared__ unsigned short Vs[64][72];      // V^T tile [d][key]
  __shared__ unsigned short Pl[4][32][72];   // wave-private P [q][key]
  const int t = threadIdx.x;
  const int w = t>>6, lane = t&63, quad = lane>>4, l15 = lane&15;
  const int bh = blockIdx.y, b = bh>>3, hp = bh&7;
  const int q0 = blockIdx.x<<7;              // 128 queries per block
  const int qs = q0 + (w<<5);                // 32 per wave
  const int* mb = mask + b*SEQ;
  const f32x4 Z4 = {0.f,0.f,0.f,0.f};
#pragma unroll
  for (int i=0;i<8;++i){
    const unsigned long long bal = __ballot(mb[i*256 + t] != 0);
    if (lane == 0) mbits[i*4 + w] = bal;
  }

  const size_t rbase = (size_t)(b*SEQ + hp*256);   // qkv row base for this bh
  bf8 qf[2][2];
#pragma unroll
  for (int a=0;a<2;++a){
    const int q = qs + a*16 + l15;
    const unsigned short* qp =
        QKV + (rbase + (q>>3))*QKV_N + (q&7)*192 + (quad<<3);
    qf[a][0] = *reinterpret_cast<const bf8*>(qp);
    qf[a][1] = *reinterpret_cast<const bf8*>(qp + 32);
  }
  const unsigned short* Vg = VT + (size_t)bh*HDIM*SEQ;

  const int srow = t>>2, sc4 = (t&3)<<4;             // staging: key row, col
  const int krow = ((srow&3)<<4) + (srow>>2);        // rho(srow)

  f32x4 of[2][4]; float lsum[2][4];
#pragma unroll
  for (int a=0;a<2;++a)
#pragma unroll
    for (int i=0;i<4;++i){ of[a][i]=Z4; lsum[a][i]=0.f; }

  // prefetch tile 0 into registers
  uint4 gk0, gk1, gv0, gv1;
  {
    const unsigned short* kp =
        QKV + (rbase + (srow>>3))*QKV_N + (srow&7)*192 + 64 + sc4;
    gk0 = *reinterpret_cast<const uint4*>(kp);
    gk1 = *reinterpret_cast<const uint4*>(kp + 8);
    const unsigned short* vp = Vg + (size_t)srow*SEQ + sc4;
    gv0 = *reinterpret_cast<const uint4*>(vp);
    gv1 = *reinterpret_cast<const uint4*>(vp + 8);
  }
  __syncthreads();                                   // mbits visible

  for (int kt=0; kt<SEQ; kt+=64){
    *reinterpret_cast<uint4*>(&Ks[krow][sc4])   = gk0;
    *reinterpret_cast<uint4*>(&Ks[krow][sc4+8]) = gk1;
    *reinterpret_cast<uint4*>(&Vs[srow][sc4])   = gv0;
    *reinterpret_cast<uint4*>(&Vs[srow][sc4+8]) = gv1;
    __syncthreads();                                 // tiles visible

    if (kt + 64 < SEQ){                              // prefetch tile t+1
      const int kk = kt + 64 + srow;
      const unsigned short* kp =
          QKV + (rbase + (kk>>3))*QKV_N + (kk&7)*192 + 64 + sc4;
      gk0 = *reinterpret_cast<const uint4*>(kp);
      gk1 = *reinterpret_cast<const uint4*>(kp + 8);
      const unsigned short* vp = Vg + (size_t)srow*SEQ + kt + 64 + sc4;
      gv0 = *reinterpret_cast<const uint4*>(vp);
      gv1 = *reinterpret_cast<const uint4*>(vp + 8);
    }

    const unsigned int msel =
        (unsigned int)(mbits[kt>>6] >> (l15<<2)) & 0xFu;

    bf8 kf0[4], kf1[4];
#pragma unroll
    for (int nf=0;nf<4;++nf){
      kf0[nf] = *reinterpret_cast<const bf8*>(&Ks[nf*16+l15][quad<<3]);
      kf1[nf] = *reinterpret_cast<const bf8*>(&Ks[nf*16+l15][32+(quad<<3)]);
    }

#pragma unroll
    for (int a=0;a<2;++a){
      f32x4 sc[4];
#pragma unroll
      for (int nf=0;nf<4;++nf){
        f32x4 s = MFMA16(qf[a][0], kf0[nf], Z4);
        sc[nf] = MFMA16(qf[a][1], kf1[nf], s);
      }
      float pv[4][4];
#pragma unroll
      for (int nf=0;nf<4;++nf){
        const bool on = (msel >> nf) & 1u;
#pragma unroll
        for (int i=0;i<4;++i)
          pv[nf][i] = on ? exp2f(sc[nf][i]) : 0.f;   // Q pre-scaled log2e/8
      }
#pragma unroll
      for (int i=0;i<4;++i)
        lsum[a][i] += (pv[0][i]+pv[1][i]) + (pv[2][i]+pv[3][i]);
#pragma unroll
      for (int i=0;i<4;++i){
        const unsigned int lo = pack_bf2(pv[0][i], pv[1][i]);
        const unsigned int hi = pack_bf2(pv[2][i], pv[3][i]);
        *reinterpret_cast<unsigned long long*>(&Pl[w][a*16+(quad<<2)+i][l15<<2]) =
            ((unsigned long long)hi<<32) | lo;
      }
    }

    bf8 pa[2][2];
#pragma unroll
    for (int a=0;a<2;++a){
      pa[a][0] = *reinterpret_cast<const bf8*>(&Pl[w][a*16+l15][quad<<3]);
      pa[a][1] = *reinterpret_cast<const bf8*>(&Pl[w][a*16+l15][32+(quad<<3)]);
    }
#pragma unroll
    for (int nf=0;nf<4;++nf){
      const bf8 v0 = *reinterpret_cast<const bf8*>(&Vs[nf*16+l15][quad<<3]);
      const bf8 v1 = *reinterpret_cast<const bf8*>(&Vs[nf*16+l15][32+(quad<<3)]);
#pragma unroll
      for (int a=0;a<2;++a){
        f32x4 o = MFMA16(pa[a][0], v0, of[a][nf]);
        of[a][nf] = MFMA16(pa[a][1], v1, o);
      }
    }
    __syncthreads();                                 // readers done, bufs free
  }

#pragma unroll
  for (int a=0;a<2;++a)
#pragma unroll
    for (int i=0;i<4;++i){
      float s = lsum[a][i];
      s += __shfl_xor(s,1); s += __shfl_xor(s,2);
      s += __shfl_xor(s,4); s += __shfl_xor(s,8);
      lsum[a][i] = s;
    }
  unsigned short* Op = O + (size_t)bh*SEQ*HDIM;
#pragma unroll
  for (int a=0;a<2;++a){
    const unsigned long long qw = mbits[(qs + a*16) >> 6];
#pragma unroll
    for (int i=0;i<4;++i){
      const int q = qs + a*16 + (quad<<2) + i;
      const bool qv = (qw >> (q & 63)) & 1ull;
      const float inv = (qv && lsum[a][i] > 0.f) ? 1.f/lsum[a][i] : 0.f;
#pragma unroll
      for (int nf=0;nf<4;++nf)
        Op[(size_t)q*HDIM + (nf<<4) + l15] = f2bf(of[a][nf][i]*inv);
    }
  }
}

// ---------------------------------------------------------------------------
// MFMA GEMM C (m97 structure): out = Ob @ WoutT^T, fp32 float4 stores.
// ---------------------------------------------------------------------------
__global__ __launch_bounds__(256) void gemm_out_mfma(
    const unsigned short* __restrict__ A, const unsigned short* __restrict__ Bt,
    float* __restrict__ Out)
{
  __shared__ unsigned short As[128][64];
  __shared__ unsigned short Bs[128][64];
  const int t = threadIdx.x;
  const int w = t>>6, lane = t&63, quad = lane>>4, l15 = lane&15;
  const int wr = (w>>1)<<6, wc = (w&1)<<6;
  const int m0 = blockIdx.y<<7, n0 = blockIdx.x<<7;
  const int row = t>>3, seg = t&7;
  const unsigned short* Agp = A  + (size_t)(m0+row)*DMODEL + seg*8;
  const unsigned short* Bgp = Bt + (size_t)(n0+row)*DMODEL + seg*8;
  f32x4 acc[4][4];
#pragma unroll
  for (int i=0;i<4;++i)
#pragma unroll
    for (int j=0;j<4;++j) acc[i][j] = (f32x4){0.f,0.f,0.f,0.f};

  for (int k0=0;k0<DMODEL;k0+=64){
    __syncthreads();
#pragma unroll
    for (int p=0;p<4;++p){
      gload_lds16(Agp + (size_t)p*32*DMODEL + k0, &As[(w<<3)+(p<<5)][0]);
      gload_lds16(Bgp + (size_t)p*32*DMODEL + k0, &Bs[(w<<3)+(p<<5)][0]);
    }
    __syncthreads();
#pragma unroll
    for (int ks=0;ks<2;++ks){
      bf8 af[4], bfr[4];
#pragma unroll
      for (int mi=0;mi<4;++mi)
        af[mi]  = *reinterpret_cast<const bf8*>(&As[wr+mi*16+l15][ks*32+quad*8]);
#pragma unroll
      for (int nj=0;nj<4;++nj)
        bfr[nj] = *reinterpret_cast<const bf8*>(&Bs[wc+(l15<<2)+nj][ks*32+quad*8]);
#pragma unroll
      for (int mi=0;mi<4;++mi)
#pragma unroll
        for (int nj=0;nj<4;++nj) acc[mi][nj] = MFMA16(af[mi], bfr[nj], acc[mi][nj]);
    }
  }
  const int cbase = n0 + wc + (l15<<2);
#pragma unroll
  for (int mi=0;mi<4;++mi)
#pragma unroll
    for (int i=0;i<4;++i){
      const int m = m0 + wr + mi*16 + quad*4 + i;
      const float4 o = make_float4(acc[mi][0][i], acc[mi][1][i],
                                   acc[mi][2][i], acc[mi][3][i]);
      *reinterpret_cast<float4*>(Out + (size_t)m*DMODEL + cbase) = o;
    }
}

// ---------------------------------------------------------------------------
extern "C" void kernel_launch(void* const* d_in, const int* in_sizes, int n_in,
                              void* d_out, int out_size, void* d_ws, size_t ws_size,
                              hipStream_t stream) {
  (void)in_sizes; (void)n_in; (void)out_size; (void)ws_size;
  const float* x     = (const float*)d_in[0];
  const int*   pmask = (const int*)d_in[2];
  const float* Wqkv  = (const float*)d_in[3];
  const float* Wout  = (const float*)d_in[4];
  float* out = (float*)d_out;

  const size_t per = (size_t)BATCH*NHEADS*SEQ*HDIM;     // 4,194,304
  unsigned short* Xh    = (unsigned short*)d_ws;
  unsigned short* WqkvT = Xh    + (size_t)8192*512;
  unsigned short* WoutT = WqkvT + (size_t)1536*512;
  unsigned short* QKVb  = WoutT + (size_t)512*512;
  unsigned short* VbT   = QKVb  + (size_t)8192*QKV_N;
  unsigned short* Ob    = VbT + per;                    // ~52 MB total

  prep<<<2304, 256, 0, stream>>>(x, Wqkv, Wout, Xh, WqkvT, WoutT);
  gemm_qkv_mfma<<<dim3(QKV_N/128, 8192/128), 256, 0, stream>>>(Xh, WqkvT, QKVb);
  v_transpose<<<dim3(SEQ/64, BATCH*NHEADS), 256, 0, stream>>>(QKVb, VbT);
  attn_mfma<<<dim3(SEQ/128, BATCH*NHEADS), 256, 0, stream>>>(QKVb, VbT, pmask, Ob);
  gemm_out_mfma<<<dim3(DMODEL/128, 8192/128), 256, 0, stream>>>(Ob, WoutT, out);
}